// Round 1
// baseline (14210.797 us; speedup 1.0000x reference)
//
#include <hip/hip_runtime.h>
#include <hip/hip_fp16.h>

#define BB 128
#define TT 500
#define HH 512
#define TWOH 1024

typedef _Float16 h2_t __attribute__((ext_vector_type(2)));

#if defined(__has_builtin)
#if __has_builtin(__builtin_amdgcn_fdot2)
#define HAVE_FDOT2 1
#endif
#endif

__device__ __forceinline__ float fdot2(unsigned a, unsigned b, float c) {
#ifdef HAVE_FDOT2
  return __builtin_amdgcn_fdot2(__builtin_bit_cast(h2_t, a),
                                __builtin_bit_cast(h2_t, b), c, false);
#else
  __half2 ah = __builtin_bit_cast(__half2, a);
  __half2 bh = __builtin_bit_cast(__half2, b);
  float2 af = __half22float2(ah);
  float2 bf = __half22float2(bh);
  return fmaf(af.x, bf.x, fmaf(af.y, bf.y, c));
#endif
}

// Convert u [2H][H] fp32 -> fp16 into workspace.
__global__ void cvt_u_kernel(const float* __restrict__ u,
                             __half* __restrict__ u16, int n) {
  int i = blockIdx.x * blockDim.x + threadIdx.x;
  if (i < n) u16[i] = __float2half(u[i]);
}

// One block per 2 batch rows. Thread j owns hidden feature j for both rows:
// computes gates[j] (at) and gates[j+H] (zt) -> h_new[j] entirely locally.
// h broadcast across the block via LDS (fp16).
__global__ __launch_bounds__(HH, 2) void ligru_kernel(
    const float* __restrict__ wx,    // [B][T][2H]
    const __half* __restrict__ u16,  // [2H][H]  (row c = uT column c)
    const float* __restrict__ ht,    // [B][H]
    const float* __restrict__ mask,  // [B][H]
    float* __restrict__ out)         // hs|zs|ats|hcs each [B][T][H]
{
  const int j = threadIdx.x;  // 0..511
  const int r0 = blockIdx.x * 2;
  const int r1 = r0 + 1;

  __shared__ alignas(16) __half hsm[2][HH];

  // u rows for this thread's two gate columns (contiguous in k)
  const uint4* ua4 = (const uint4*)(u16 + (size_t)j * HH);
  const uint4* uz4 = (const uint4*)(u16 + (size_t)(j + HH) * HH);

  const float m0 = mask[(size_t)r0 * HH + j];
  const float m1 = mask[(size_t)r1 * HH + j];

  float h0 = ht[(size_t)r0 * HH + j];
  float h1 = ht[(size_t)r1 * HH + j];

  hsm[0][j] = __float2half(h0);
  hsm[1][j] = __float2half(h1);
  __syncthreads();

  const size_t BTH = (size_t)BB * TT * HH;
  float* out_h = out;
  float* out_z = out + BTH;
  float* out_a = out + 2 * BTH;
  float* out_hc = out + 3 * BTH;

  const float* wx0 = wx + (size_t)r0 * TT * TWOH;
  const float* wx1 = wx + (size_t)r1 * TT * TWOH;

  const uint4* h04 = (const uint4*)&hsm[0][0];
  const uint4* h14 = (const uint4*)&hsm[1][0];

  for (int t = 0; t < TT; ++t) {
    // wx loads issued early: independent of h, latency hides under dot loop
    const float wa0 = wx0[(size_t)t * TWOH + j];
    const float wz0 = wx0[(size_t)t * TWOH + HH + j];
    const float wa1 = wx1[(size_t)t * TWOH + j];
    const float wz1 = wx1[(size_t)t * TWOH + HH + j];

    float a0 = 0.f, a1 = 0.f, z0 = 0.f, z1 = 0.f;
#pragma unroll 8
    for (int kk = 0; kk < HH / 8; ++kk) {  // 8 halves (16B) per iter
      uint4 va = ua4[kk];
      uint4 vz = uz4[kk];
      uint4 p0 = h04[kk];  // LDS broadcast (all lanes same addr)
      uint4 p1 = h14[kk];
      a0 = fdot2(va.x, p0.x, a0);
      a1 = fdot2(va.x, p1.x, a1);
      z0 = fdot2(vz.x, p0.x, z0);
      z1 = fdot2(vz.x, p1.x, z1);
      a0 = fdot2(va.y, p0.y, a0);
      a1 = fdot2(va.y, p1.y, a1);
      z0 = fdot2(vz.y, p0.y, z0);
      z1 = fdot2(vz.y, p1.y, z1);
      a0 = fdot2(va.z, p0.z, a0);
      a1 = fdot2(va.z, p1.z, a1);
      z0 = fdot2(vz.z, p0.z, z0);
      z1 = fdot2(vz.z, p1.z, z1);
      a0 = fdot2(va.w, p0.w, a0);
      a1 = fdot2(va.w, p1.w, a1);
      z0 = fdot2(vz.w, p0.w, z0);
      z1 = fdot2(vz.w, p1.w, z1);
    }

    const float at0 = wa0 + a0, at1 = wa1 + a1;
    const float zp0 = wz0 + z0, zp1 = wz1 + z1;
    const float zt0 = 1.f / (1.f + __expf(-zp0));
    const float zt1 = 1.f / (1.f + __expf(-zp1));
    const float hc0 = fmaxf(at0, 0.f) * m0;
    const float hc1 = fmaxf(at1, 0.f) * m1;
    h0 = h0 * zt0 + (1.f - zt0) * hc0;
    h1 = h1 * zt1 + (1.f - zt1) * hc1;

    const size_t o0 = (size_t)r0 * TT * HH + (size_t)t * HH + j;
    const size_t o1 = (size_t)r1 * TT * HH + (size_t)t * HH + j;
    out_h[o0] = h0;
    out_z[o0] = zt0;
    out_a[o0] = at0;
    out_hc[o0] = hc0;
    out_h[o1] = h1;
    out_z[o1] = zt1;
    out_a[o1] = at1;
    out_hc[o1] = hc1;

    __syncthreads();  // everyone done reading hsm for step t
    hsm[0][j] = __float2half(h0);
    hsm[1][j] = __float2half(h1);
    __syncthreads();  // h_new visible for step t+1
  }
}

extern "C" void kernel_launch(void* const* d_in, const int* in_sizes, int n_in,
                              void* d_out, int out_size, void* d_ws,
                              size_t ws_size, hipStream_t stream) {
  const float* wx = (const float*)d_in[0];
  const float* u = (const float*)d_in[1];
  const float* ht = (const float*)d_in[2];
  const float* mask = (const float*)d_in[3];
  float* out = (float*)d_out;

  __half* u16 = (__half*)d_ws;  // 1 MB

  const int n = TWOH * HH;
  hipLaunchKernelGGL(cvt_u_kernel, dim3((n + 255) / 256), dim3(256), 0, stream,
                     u, u16, n);
  hipLaunchKernelGGL(ligru_kernel, dim3(BB / 2), dim3(HH), 0, stream, wx, u16,
                     ht, mask, out);
}

// Round 2
// 4006.140 us; speedup vs baseline: 3.5473x; 3.5473x over previous
//
#include <hip/hip_runtime.h>
#include <hip/hip_fp16.h>

#define BB 128
#define TT 500
#define HH 512
#define TWOH 1024
#define NG 8     // row groups
#define GM 16    // rows per group
#define NBPG 8   // blocks per group (c-split)
#define KB 16    // k-tiles of 32 (512/32)

typedef _Float16 f16x8 __attribute__((ext_vector_type(8)));
typedef float f32x4 __attribute__((ext_vector_type(4)));

// workspace layout (in halves/words from base):
//   u16  : [0, 524288) halves          (1 MiB)
//   hx   : [524288, +131072) halves    (256 KiB)  [g][parity][16][512]
//   ctrs : next, 512 u32               (2 KiB)    group g uses ctrs[g*64]
#define WS_U16_HALVES 524288
#define WS_HX_HALVES  131072

__global__ void prep_kernel(const float* __restrict__ u,
                            const float* __restrict__ ht,
                            __half* __restrict__ u16,
                            __half* __restrict__ hx,
                            unsigned int* __restrict__ ctrs) {
  int i = blockIdx.x * blockDim.x + threadIdx.x;
  if (i < WS_U16_HALVES) u16[i] = __float2half(u[i]);
  if (i < BB * HH) {  // hx[parity=0] <- ht
    int R = i >> 9, k = i & 511;
    int g = R >> 4, m = R & 15;
    hx[(size_t)g * (2 * GM * HH) + m * HH + k] = __float2half(ht[i]);
  }
  if (i < 512) ctrs[i] = 0;
}

__global__ __launch_bounds__(256) void ligru_mfma(
    const float* __restrict__ wx, const __half* __restrict__ u16,
    const float* __restrict__ ht, const float* __restrict__ mask,
    float* __restrict__ out, __half* __restrict__ hx,
    unsigned int* __restrict__ ctrs) {
  const int tid = threadIdx.x;
  const int lane = tid & 63;
  const int w = tid >> 6;    // wave 0..3
  const int l15 = lane & 15;
  const int q = lane >> 4;   // 0..3
  const int b = blockIdx.x;
  const int g = b & 7;       // group (blockIdx%8 -> same-XCD heuristic; correctness via agent-scope atomics)
  const int s = b >> 3;      // c-slice 0..7

  const bool is_at = (w < 2);
  const int wj = is_at ? w : (w - 2);
  const int j0 = s * 64 + wj * 32;        // hidden-col base (32 wide)
  const int cabs = is_at ? j0 : (HH + j0);
  const int row0 = g * GM;

  __shared__ char h16[GM * HH * 2];  // 16 KiB fp16, XOR-swizzled rows
  __shared__ float atx[GM * 64];     // 4 KiB at exchange

  unsigned int* ctr = ctrs + g * 64;
  __half* hxg = hx + (size_t)g * (2 * GM * HH);

  // ---- B-frags (u), persistent: 32 x f16x8 = 128 VGPR
  f16x8 bf[KB][2];
#pragma unroll
  for (int kb = 0; kb < KB; ++kb)
#pragma unroll
    for (int nt = 0; nt < 2; ++nt) {
      const uint4* p = (const uint4*)(u16 + (size_t)(cabs + nt * 16 + l15) * HH + kb * 32 + q * 8);
      uint4 v = *p;
      bf[kb][nt] = __builtin_bit_cast(f16x8, v);
    }

  // ---- persistent per-lane state (rows m=4q+r, col j0+nt*16+l15)
  float hreg[2][4], mreg[2][4];
#pragma unroll
  for (int nt = 0; nt < 2; ++nt)
#pragma unroll
    for (int r = 0; r < 4; ++r) {
      int m = 4 * q + r;
      size_t off = (size_t)(row0 + m) * HH + j0 + nt * 16 + l15;
      mreg[nt][r] = mask[off];
      hreg[nt][r] = ht[off];
    }

  const size_t BTH = (size_t)BB * TT * HH;
  float* out_h = out;
  float* out_z = out + BTH;
  float* out_a = out + 2 * BTH;
  float* out_hc = out + 3 * BTH;

  for (int t = 0; t < TT; ++t) {
    // wx prefetch: h-independent, issued before the spin so HBM latency hides
    float wxr[2][4];
#pragma unroll
    for (int nt = 0; nt < 2; ++nt)
#pragma unroll
      for (int r = 0; r < 4; ++r) {
        int m = 4 * q + r;
        wxr[nt][r] = wx[((size_t)(row0 + m) * TT + t) * TWOH + cabs + nt * 16 + l15];
      }

    if (t > 0) {
      if (tid == 0) {
        const unsigned int target = (unsigned)(NBPG * t);
        while (__hip_atomic_load(ctr, __ATOMIC_RELAXED, __HIP_MEMORY_SCOPE_AGENT) < target)
          __builtin_amdgcn_s_sleep(1);
      }
      __syncthreads();
    }

    // phase 1: h_x[t&1] (coherent point) -> LDS, row-XOR swizzle
    {
      unsigned int* hsrc = (unsigned int*)(hxg + (t & 1) * (GM * HH));
#pragma unroll
      for (int p = 0; p < 16; ++p) {
        int word = tid + p * 256;  // 4096 words total
        unsigned int v = __hip_atomic_load(hsrc + word, __ATOMIC_RELAXED, __HIP_MEMORY_SCOPE_AGENT);
        int byte = word * 4;
        int r = byte >> 10;
        *(unsigned int*)(h16 + (byte ^ ((r & 7) << 4))) = v;
      }
    }
    __syncthreads();

    // phase 2: A-frags from LDS + MFMA (A: row=l15, k-chunk=q; B mirrored)
    f32x4 acc0 = {0.f, 0.f, 0.f, 0.f}, acc1 = {0.f, 0.f, 0.f, 0.f};
#pragma unroll
    for (int kb = 0; kb < KB; ++kb) {
      int off = (l15 * 1024 + kb * 64 + q * 16) ^ ((l15 & 7) << 4);
      f16x8 af = *(const f16x8*)(h16 + off);
      acc0 = __builtin_amdgcn_mfma_f32_16x16x32_f16(af, bf[kb][0], acc0, 0, 0, 0);
      acc1 = __builtin_amdgcn_mfma_f32_16x16x32_f16(af, bf[kb][1], acc1, 0, 0, 0);
    }

    float gate[2][4];
#pragma unroll
    for (int r = 0; r < 4; ++r) {
      gate[0][r] = acc0[r] + wxr[0][r];
      gate[1][r] = acc1[r] + wxr[1][r];
    }

    // phase 3: at-waves publish at-tiles for the paired zt-waves
    if (is_at) {
#pragma unroll
      for (int nt = 0; nt < 2; ++nt)
#pragma unroll
        for (int r = 0; r < 4; ++r)
          atx[(4 * q + r) * 64 + wj * 32 + nt * 16 + l15] = gate[nt][r];
    }
    __syncthreads();

    __half* hdst = hxg + ((t + 1) & 1) * (GM * HH);
#pragma unroll
    for (int nt = 0; nt < 2; ++nt)
#pragma unroll
      for (int r = 0; r < 4; ++r) {
        int m = 4 * q + r;
        int j = j0 + nt * 16 + l15;
        size_t oidx = ((size_t)(row0 + m) * TT + t) * HH + j;
        if (is_at) {
          float at = gate[nt][r];
          float hc = fmaxf(at, 0.f) * mreg[nt][r];
          out_a[oidx] = at;
          out_hc[oidx] = hc;
        } else {
          float at = atx[m * 64 + wj * 32 + nt * 16 + l15];
          float zt = 1.f / (1.f + __expf(-gate[nt][r]));
          float hc = fmaxf(at, 0.f) * mreg[nt][r];
          float hn = hreg[nt][r] * zt + (1.f - zt) * hc;  // fp32 master state
          hreg[nt][r] = hn;
          out_z[oidx] = zt;
          out_h[oidx] = hn;
          __hip_atomic_store((unsigned short*)hdst + m * HH + j,
                             __half_as_ushort(__float2half(hn)),
                             __ATOMIC_RELAXED, __HIP_MEMORY_SCOPE_AGENT);
        }
      }

    __syncthreads();  // drains vmcnt(0): all agent-scope h stores globally visible
    if (tid == 0)
      __hip_atomic_fetch_add(ctr, 1u, __ATOMIC_RELEASE, __HIP_MEMORY_SCOPE_AGENT);
  }
}

extern "C" void kernel_launch(void* const* d_in, const int* in_sizes, int n_in,
                              void* d_out, int out_size, void* d_ws,
                              size_t ws_size, hipStream_t stream) {
  const float* wx = (const float*)d_in[0];
  const float* u = (const float*)d_in[1];
  const float* ht = (const float*)d_in[2];
  const float* mask = (const float*)d_in[3];
  float* out = (float*)d_out;

  __half* u16 = (__half*)d_ws;
  __half* hxp = u16 + WS_U16_HALVES;
  unsigned int* ctrs = (unsigned int*)(hxp + WS_HX_HALVES);

  hipLaunchKernelGGL(prep_kernel, dim3(2048), dim3(256), 0, stream, u, ht, u16,
                     hxp, ctrs);
  hipLaunchKernelGGL(ligru_mfma, dim3(NG * NBPG), dim3(256), 0, stream, wx, u16,
                     ht, mask, out, hxp, ctrs);
}